// Round 2
// baseline (225.731 us; speedup 1.0000x reference)
//
#include <hip/hip_runtime.h>

#define HH 256
#define WW 256
#define HWPX 65536
#define BB 8
#define KK 21
#define CC 32
#define RECB 80   // px record: 64B f16 feats (4x float4) + 8B (T, |q|^2) + 8B pad

typedef _Float16 half2v __attribute__((ext_vector_type(2)));
union F4H { float4 f4; half2v h[4]; };

// ---------------- kernel 1 (fused): T + |q|^2 + interleaved f16 record, 1 px/thread ----------------
// 2048 blocks -> 8 blocks/CU (100% occupancy cap). Scalar 4B plane loads stay coalesced.
// Record layout (80 B, 16B-aligned): [0..63] 32ch f16, [64] T(f32), [68] |q|^2(f32), [72..79] pad.
// One record per pixel -> affinity needs ONE address per neighbor, loads at immediate offsets.
__global__ __launch_bounds__(256) void prep(const float* __restrict__ cls,
                                            const float* __restrict__ feat,
                                            char* __restrict__ rec) {
    const int tid = blockIdx.x * 256 + threadIdx.x;   // 0..524287 (b*HWPX+p)
    const int b = tid >> 16;
    const int p = tid & (HWPX - 1);

    // T = sum_k S
    const float* cbase = cls + (size_t)b * KK * HWPX + p;
    float T = 0.f;
#pragma unroll
    for (int k = 0; k < KK; ++k) T += cbase[(size_t)k * HWPX];

    const float* src = feat + (size_t)b * CC * HWPX + p;
    char* r = rec + (size_t)tid * RECB;
    float nq = 0.f;
#pragma unroll
    for (int j = 0; j < 4; ++j) {
        F4H u;
#pragma unroll
        for (int k = 0; k < 4; ++k) {
            float a  = src[(size_t)(j * 8 + 2 * k) * HWPX];
            float b2 = src[(size_t)(j * 8 + 2 * k + 1) * HWPX];
            u.h[k] = __builtin_bit_cast(half2v, __builtin_amdgcn_cvt_pkrtz(a, b2));
            nq = __builtin_amdgcn_fdot2(u.h[k], u.h[k], nq, false);
        }
        *(float4*)(r + j * 16) = u.f4;
    }
    *(float2*)(r + 64) = make_float2(T, nq);
}

// ---------------- kernel 2 (hot): affinity, 4 stacked px/thread, interleaved records ----------------
// w(p,q) = exp(-off^2/16 - (|p|^2+|q|^2-2 p.q)); acc telescopes, w = exp2(2*log2e*acc).
// dyi split across 2 blocks (grid 1024 = 4 waves/SIMD). Per neighbor column: ONE base address,
// 5 loads at immediate offsets (vs 5 base pointers + ~16 addr insts before).
__global__ __launch_bounds__(256) void affinity4(const char* __restrict__ rec,
                                                 float* __restrict__ V,
                                                 float* __restrict__ deg) {
    // XCD swizzle: L%8 = batch so each XCD's share is one batch (records ~5.2 MB, L2-resident)
    const int L  = blockIdx.x;            // 0..1023
    const int b  = L & 7;
    const int t  = L >> 3;                // 0..127
    const int by = t & 15;
    const int bx = (t >> 4) & 3;          // 0..3
    const int half = t >> 6;              // 0..1 : dyi chunk
    const int lane = threadIdx.x & 63;
    const int wid  = threadIdx.x >> 6;
    const int gx  = bx * 64 + lane;
    const int gy0 = by * 16 + wid * 4;    // owns rows gy0..gy0+3

    const char* rb = rec + (size_t)b * HWPX * RECB;

    F4H fp[4][4];
    float np_[4];
#pragma unroll
    for (int py = 0; py < 4; ++py) {
        const int pp = ((gy0 + py) << 8) | gx;
        const char* rp = rb + (size_t)pp * RECB;
        fp[py][0].f4 = *(const float4*)(rp);
        fp[py][1].f4 = *(const float4*)(rp + 16);
        fp[py][2].f4 = *(const float4*)(rp + 32);
        fp[py][3].f4 = *(const float4*)(rp + 48);
        np_[py] = *(const float*)(rp + 68);
    }

    float degacc[4] = {0.f, 0.f, 0.f, 0.f};
    float vacc[4]   = {0.f, 0.f, 0.f, 0.f};

    const int dy_lo = half * 6;
    const int dy_hi = dy_lo + 6;

#pragma unroll 1   // runtime row loop: caps load-hoisting window (round-3 spill lesson)
    for (int dyi = dy_lo; dyi < dy_hi; ++dyi) {
        const int ny = gy0 + dyi - 4;               // neighbor row, same for all py
        if ((unsigned)ny >= HH) continue;           // uniform: OOB row contributes 0
        const char* rowbase = rb + (size_t)(ny << 8) * RECB;

        int dy2[4];
        float base[4];
#pragma unroll
        for (int py = 0; py < 4; ++py) {
            const int d = dyi - 4 - py;             // uniform
            dy2[py] = d * d;
            base[py] = fmaf(-0.03125f, (float)dy2[py], -0.5f * np_[py]);
        }
        const int mind = min(min(dy2[0], dy2[1]), min(dy2[2], dy2[3]));

#pragma unroll 3
        for (int dxi = 0; dxi < 9; ++dxi) {
            const int dx = dxi - 4;                 // uniform
            const int dx2 = dx * dx;
            if (mind + dx2 >= 25) continue;         // uniform: no py uses this column

            const int gx2 = gx + dx;
            const bool vx = (unsigned)gx2 < WW;     // per-lane x bound
            const int qx = min(max(gx2, 0), WW - 1);
            const char* rq = rowbase + (size_t)qx * RECB;

            F4H nb0, nb1, nb2, nb3;
            nb0.f4 = *(const float4*)(rq);
            nb1.f4 = *(const float4*)(rq + 16);
            nb2.f4 = *(const float4*)(rq + 32);
            nb3.f4 = *(const float4*)(rq + 48);
            const float2 tq = *(const float2*)(rq + 64);
            const float cdx = (float)dx2 * -0.03125f;

#pragma unroll
            for (int py = 0; py < 4; ++py) {
                if (dy2[py] + dx2 < 25) {           // uniform circle test
                    float acc = fmaf(-0.5f, tq.y, base[py] + cdx);
#pragma unroll
                    for (int k = 0; k < 4; ++k) {
                        acc = __builtin_amdgcn_fdot2(fp[py][0].h[k], nb0.h[k], acc, false);
                        acc = __builtin_amdgcn_fdot2(fp[py][1].h[k], nb1.h[k], acc, false);
                        acc = __builtin_amdgcn_fdot2(fp[py][2].h[k], nb2.h[k], acc, false);
                        acc = __builtin_amdgcn_fdot2(fp[py][3].h[k], nb3.h[k], acc, false);
                    }
                    float w = __builtin_exp2f(acc * 2.8853900817779268f);  // exp(2*acc)
                    w = vx ? w : 0.f;
                    degacc[py] += w;
                    vacc[py] = fmaf(w, tq.x, vacc[py]);
                }
            }
        }
    }

    float* Vh = V   + (size_t)half * (BB * HWPX);
    float* Dh = deg + (size_t)half * (BB * HWPX);
    const size_t bofs = (size_t)b * HWPX;
#pragma unroll
    for (int py = 0; py < 4; ++py) {
        const size_t o = bofs + ((size_t)(gy0 + py) << 8) + gx;
        Vh[o] = vacc[py];
        Dh[o] = degacc[py];
    }
}

// ---------------- kernel 3: per-(b,j) numer/denom, 1 px/thread, 100% occupancy cap ----------------
// grid (256, 8) = 2048 blocks = 8 blocks/CU (was 512 blocks = 25% cap -> latency-bound risk).
__global__ __launch_bounds__(256) void reduce_bj(const float* __restrict__ cls,
                                                 const float* __restrict__ V,
                                                 const float* __restrict__ deg,
                                                 float* __restrict__ numer,
                                                 float* __restrict__ denom) {
    __shared__ float smN[4][22], smD[4][22];
    const int b = blockIdx.y;
    const int p = blockIdx.x * 256 + threadIdx.x;          // 0..65535
    const size_t bp = (size_t)b * HWPX + p;

    const float v = V[bp] + V[(size_t)BB * HWPX + bp];     // fold the two dyi-halves
    const float d = deg[bp] + deg[(size_t)BB * HWPX + bp];
    const float* clsb = cls + (size_t)b * KK * HWPX + p;

    float accN[KK], accD[KK];
#pragma unroll
    for (int j = 0; j < KK; ++j) {
        const float s = clsb[(size_t)j * HWPX];
        accN[j] = s * v;
        accD[j] = s * d;
    }

    const int wid = threadIdx.x >> 6;
#pragma unroll
    for (int j = 0; j < KK; ++j) {
        float n = accN[j], dd = accD[j];
#pragma unroll
        for (int off = 32; off > 0; off >>= 1) {
            n  += __shfl_down(n, off);
            dd += __shfl_down(dd, off);
        }
        if ((threadIdx.x & 63) == 0) { smN[wid][j] = n; smD[wid][j] = dd; }
    }
    __syncthreads();
    if (threadIdx.x < 2 * KK) {
        int half = threadIdx.x / KK;
        int j = threadIdx.x - half * KK;
        float acc = half ? (smD[0][j] + smD[1][j] + smD[2][j] + smD[3][j])
                         : (smN[0][j] + smN[1][j] + smN[2][j] + smN[3][j]);
        float* dst = half ? denom : numer;
        atomicAdd(&dst[b * KK + j], acc);
    }
}

// ---------------- kernel 4: out = sum_{b,j} numer/denom ----------------
__global__ __launch_bounds__(256) void finalize(const float* __restrict__ numer,
                                                const float* __restrict__ denom,
                                                float* __restrict__ out) {
    __shared__ float sm[4];
    int i = threadIdx.x;
    float r = 0.f;
    if (i < BB * KK) r = numer[i] / denom[i];
#pragma unroll
    for (int off = 32; off > 0; off >>= 1) r += __shfl_down(r, off);
    if ((i & 63) == 0) sm[i >> 6] = r;
    __syncthreads();
    if (i == 0) out[0] = sm[0] + sm[1] + sm[2] + sm[3];
}

extern "C" void kernel_launch(void* const* d_in, const int* in_sizes, int n_in,
                              void* d_out, int out_size, void* d_ws, size_t ws_size,
                              hipStream_t stream) {
    const float* cls  = (const float*)d_in[0];  // [B,K,H,W]
    const float* feat = (const float*)d_in[1];  // [B,C,H,W]
    float* out = (float*)d_out;

    const size_t BHW = (size_t)BB * HWPX;
    // rec (41.9 MB) | V[2 halves] (4.2 MB) | deg[2] (4.2 MB) | numer | denom  (~50.4 MB)
    char*  rc   = (char*)d_ws;
    float* V    = (float*)(rc + BHW * RECB);     // 2*BHW floats
    float* dg   = V + 2 * BHW;                   // 2*BHW floats
    float* numer = dg + 2 * BHW;
    float* denom = numer + BB * KK;

    (void)hipMemsetAsync(numer, 0, 2 * BB * KK * sizeof(float), stream);
    prep<<<dim3((BB * HWPX) / 256), dim3(256), 0, stream>>>(cls, feat, rc);
    affinity4<<<dim3(1024), dim3(256), 0, stream>>>(rc, V, dg);
    reduce_bj<<<dim3(HWPX / 256, BB), dim3(256), 0, stream>>>(cls, V, dg, numer, denom);
    finalize<<<dim3(1), dim3(256), 0, stream>>>(numer, denom, out);
}

// Round 3
// 198.820 us; speedup vs baseline: 1.1354x; 1.1354x over previous
//
#include <hip/hip_runtime.h>

#define HH 256
#define WW 256
#define HWPX 65536
#define BB 8
#define KK 21
#define CC 32

typedef _Float16 half2v __attribute__((ext_vector_type(2)));
union F4H { float4 f4; half2v h[4]; };

// ---------------- kernel 1 (fused): T + |q|^2 + planar f16 pack, 1 px/thread ----------------
// ROUND-1 VERBATIM (known good): planar float4 stores are lane-contiguous (coalesced);
// round-2's 80B-record scatter stores caused ~4x write amplification (+25 us). Reverted.
// 2048 blocks -> 8 blocks/CU (100% occupancy cap).
__global__ __launch_bounds__(256) void prep(const float* __restrict__ cls,
                                            const float* __restrict__ feat,
                                            float4* __restrict__ fpk,
                                            float2* __restrict__ TN) {
    const int tid = blockIdx.x * 256 + threadIdx.x;   // 0..524287 (b*HWPX+p)
    const int b = tid >> 16;
    const int p = tid & (HWPX - 1);

    // T = sum_k S
    const float* cbase = cls + (size_t)b * KK * HWPX + p;
    float T = 0.f;
#pragma unroll
    for (int k = 0; k < KK; ++k) T += cbase[(size_t)k * HWPX];

    const float* src = feat + (size_t)b * CC * HWPX + p;
    float nq = 0.f;
#pragma unroll
    for (int j = 0; j < 4; ++j) {
        F4H u;
#pragma unroll
        for (int k = 0; k < 4; ++k) {
            float a  = src[(size_t)(j * 8 + 2 * k) * HWPX];
            float b2 = src[(size_t)(j * 8 + 2 * k + 1) * HWPX];
            u.h[k] = __builtin_bit_cast(half2v, __builtin_amdgcn_cvt_pkrtz(a, b2));
            nq = __builtin_amdgcn_fdot2(u.h[k], u.h[k], nq, false);
        }
        fpk[(size_t)j * (BB * HWPX) + tid] = u.f4;    // lane-contiguous 16B stores
    }
    TN[tid] = make_float2(T, nq);
}

// ---------------- kernel 2 (hot): affinity + FUSED per-(b,j) reduction ----------------
// w(p,q) = exp(-off^2/16 - (|p|^2+|q|^2-2 p.q)); acc telescopes, w = exp2(2*log2e*acc).
// dyi split across 2 blocks (grid 1024 = 4 blocks/CU). Each half computes PARTIAL V/deg for
// its 4 px; since N_j = sum_p S_j(p)(V0+V1)(p) distributes, each half multiplies its partial
// by cls and atomicAdds -> reduce_bj kernel + V/deg round-trip (33.6 MB) deleted.
// fdot2 chain split 16-deep -> 4x4-deep independent chains (+3 adds, 1/4 critical path).
__global__ __launch_bounds__(256, 4) void affinity4(const float4* __restrict__ fpk,
                                                    const float2* __restrict__ TN,
                                                    const float* __restrict__ cls,
                                                    float* __restrict__ numer,
                                                    float* __restrict__ denom) {
    __shared__ float smN[4][22], smD[4][22];
    // XCD swizzle: L%8 = batch so each XCD's share is one batch (~4.7 MB, mostly L2-resident)
    const int L  = blockIdx.x;            // 0..1023
    const int b  = L & 7;
    const int t  = L >> 3;                // 0..127
    const int by = t & 15;
    const int bx = (t >> 4) & 3;          // 0..3
    const int half = t >> 6;              // 0..1 : dyi chunk
    const int lane = threadIdx.x & 63;
    const int wid  = threadIdx.x >> 6;
    const int gx  = bx * 64 + lane;
    const int gy0 = by * 16 + wid * 4;    // owns rows gy0..gy0+3

    const size_t bofs = (size_t)b * HWPX;
    const float4* fb0 = fpk + bofs;
    const float4* fb1 = fpk + (size_t)1 * BB * HWPX + bofs;
    const float4* fb2 = fpk + (size_t)2 * BB * HWPX + bofs;
    const float4* fb3 = fpk + (size_t)3 * BB * HWPX + bofs;
    const float2* tnb = TN + bofs;

    F4H fp[4][4];
    float np_[4];
#pragma unroll
    for (int py = 0; py < 4; ++py) {
        const int pp = ((gy0 + py) << 8) | gx;
        fp[py][0].f4 = fb0[pp];
        fp[py][1].f4 = fb1[pp];
        fp[py][2].f4 = fb2[pp];
        fp[py][3].f4 = fb3[pp];
        np_[py] = tnb[pp].y;
    }

    float degacc[4] = {0.f, 0.f, 0.f, 0.f};
    float vacc[4]   = {0.f, 0.f, 0.f, 0.f};

    const int dy_lo = half * 6;
    const int dy_hi = dy_lo + 6;

#pragma unroll 1   // runtime row loop: caps load-hoisting window (round-3 spill lesson)
    for (int dyi = dy_lo; dyi < dy_hi; ++dyi) {
        const int ny = gy0 + dyi - 4;               // neighbor row, same for all py
        if ((unsigned)ny >= HH) continue;           // uniform: OOB row contributes 0
        const int rowq = ny << 8;

        int dy2[4];
        float base[4];
#pragma unroll
        for (int py = 0; py < 4; ++py) {
            const int d = dyi - 4 - py;             // uniform
            dy2[py] = d * d;
            base[py] = fmaf(-0.03125f, (float)dy2[py], -0.5f * np_[py]);
        }
        const int mind = min(min(dy2[0], dy2[1]), min(dy2[2], dy2[3]));

#pragma unroll 3
        for (int dxi = 0; dxi < 9; ++dxi) {
            const int dx = dxi - 4;                 // uniform
            const int dx2 = dx * dx;
            if (mind + dx2 >= 25) continue;         // uniform: no py uses this column

            const int gx2 = gx + dx;
            const bool vx = (unsigned)gx2 < WW;     // per-lane x bound
            const int q = rowq | min(max(gx2, 0), WW - 1);

            F4H nb0, nb1, nb2, nb3;
            nb0.f4 = fb0[q];
            nb1.f4 = fb1[q];
            nb2.f4 = fb2[q];
            nb3.f4 = fb3[q];
            const float2 tq = tnb[q];
            const float cdx = (float)dx2 * -0.03125f;

#pragma unroll
            for (int py = 0; py < 4; ++py) {
                if (dy2[py] + dx2 < 25) {           // uniform circle test
                    // 4 independent 4-deep fdot2 chains (was one 16-deep serial chain)
                    float c0 = fmaf(-0.5f, tq.y, base[py] + cdx);
                    float c1 = 0.f, c2 = 0.f, c3 = 0.f;
#pragma unroll
                    for (int k = 0; k < 4; ++k) {
                        c0 = __builtin_amdgcn_fdot2(fp[py][0].h[k], nb0.h[k], c0, false);
                        c1 = __builtin_amdgcn_fdot2(fp[py][1].h[k], nb1.h[k], c1, false);
                        c2 = __builtin_amdgcn_fdot2(fp[py][2].h[k], nb2.h[k], c2, false);
                        c3 = __builtin_amdgcn_fdot2(fp[py][3].h[k], nb3.h[k], c3, false);
                    }
                    const float acc = (c0 + c1) + (c2 + c3);
                    float w = __builtin_exp2f(acc * 2.8853900817779268f);  // exp(2*acc)
                    w = vx ? w : 0.f;
                    degacc[py] += w;
                    vacc[py] = fmaf(w, tq.x, vacc[py]);
                }
            }
        }
    }

    // ---- fused reduce: N_j += sum_py S_j(px_py) * vacc[py], D_j likewise (partial halves add) ----
    const float* clsb = cls + (size_t)b * KK * HWPX;
#pragma unroll 1
    for (int jc = 0; jc < 3; ++jc) {                // 3 chunks of 7 j's: caps live registers
        float accN[7], accD[7];
#pragma unroll
        for (int jj = 0; jj < 7; ++jj) {
            const float* cj = clsb + (size_t)(jc * 7 + jj) * HWPX;
            float n = 0.f, d = 0.f;
#pragma unroll
            for (int py = 0; py < 4; ++py) {
                const float s = cj[((gy0 + py) << 8) | gx];
                n = fmaf(s, vacc[py], n);
                d = fmaf(s, degacc[py], d);
            }
            accN[jj] = n; accD[jj] = d;
        }
#pragma unroll
        for (int jj = 0; jj < 7; ++jj) {
            float n = accN[jj], d = accD[jj];
#pragma unroll
            for (int off = 32; off > 0; off >>= 1) {
                n += __shfl_down(n, off);
                d += __shfl_down(d, off);
            }
            if (lane == 0) { smN[wid][jc * 7 + jj] = n; smD[wid][jc * 7 + jj] = d; }
        }
    }
    __syncthreads();
    if (threadIdx.x < 2 * KK) {
        const int h2 = threadIdx.x / KK;
        const int j = threadIdx.x - h2 * KK;
        const float a = h2 ? (smD[0][j] + smD[1][j] + smD[2][j] + smD[3][j])
                           : (smN[0][j] + smN[1][j] + smN[2][j] + smN[3][j]);
        atomicAdd((h2 ? denom : numer) + b * KK + j, a);
    }
}

// ---------------- kernel 3: out = sum_{b,j} numer/denom ----------------
__global__ __launch_bounds__(256) void finalize(const float* __restrict__ numer,
                                                const float* __restrict__ denom,
                                                float* __restrict__ out) {
    __shared__ float sm[4];
    int i = threadIdx.x;
    float r = 0.f;
    if (i < BB * KK) r = numer[i] / denom[i];
#pragma unroll
    for (int off = 32; off > 0; off >>= 1) r += __shfl_down(r, off);
    if ((i & 63) == 0) sm[i >> 6] = r;
    __syncthreads();
    if (i == 0) out[0] = sm[0] + sm[1] + sm[2] + sm[3];
}

extern "C" void kernel_launch(void* const* d_in, const int* in_sizes, int n_in,
                              void* d_out, int out_size, void* d_ws, size_t ws_size,
                              hipStream_t stream) {
    const float* cls  = (const float*)d_in[0];  // [B,K,H,W]
    const float* feat = (const float*)d_in[1];  // [B,C,H,W]
    float* out = (float*)d_out;

    const size_t BHW = (size_t)BB * HWPX;
    // fpk (33.5 MB) | TN (4.2 MB) | numer | denom   (~38 MB)
    float4* fpk  = (float4*)d_ws;
    float2* TN   = (float2*)((char*)d_ws + BHW * 64);
    float*  numer = (float*)((char*)TN + BHW * 8);
    float*  denom = numer + BB * KK;

    (void)hipMemsetAsync(numer, 0, 2 * BB * KK * sizeof(float), stream);
    prep<<<dim3((BB * HWPX) / 256), dim3(256), 0, stream>>>(cls, feat, fpk, TN);
    affinity4<<<dim3(1024), dim3(256), 0, stream>>>(fpk, TN, cls, numer, denom);
    finalize<<<dim3(1), dim3(256), 0, stream>>>(numer, denom, out);
}